// Round 2
// baseline (131.260 us; speedup 1.0000x reference)
//
#include <hip/hip_runtime.h>

// net_86698209837440: N=100000, DEG=32 (edges sorted by tgt, deg==32), D=24, NK=2, H=64.
// R9 = R8 with ext_vector_type pointers for nontemporal builtins (HIP_vector_type
// float4/int4/ushort4 are classes -> rejected by __builtin_nontemporal_*).
//  - depth-3 node gather pipeline (g[3][16]): steady-state exposed gather-miss
//    latency per node drops from ~(L - t) to ~(L - 2t); phase 1 is dominated by
//    ~900cyc per-XCD compulsory HBM misses on the 4.8MB bf16 table.
//  - nontemporal hints on all streamed-once traffic (ei/kv staging, out stores,
//    xcvt in/out) so the gather table isn't evicted from L2 by streams.

#define NN   100000
#define DEG  32
#define EE   (NN * DEG)
#define DD   24
#define HH   64
#define NPB  32            // nodes per block; 100000 = 3125 * 32 exact
#define TPB  256
#define NPW  8             // nodes per wave
#define PST  56            // pre_s row stride (ushorts)

typedef __attribute__((ext_vector_type(8)))  short short8;
typedef __attribute__((ext_vector_type(16))) float float16;
typedef __attribute__((ext_vector_type(4)))  float f32x4;
typedef __attribute__((ext_vector_type(4)))  int   i32x4;
typedef __attribute__((ext_vector_type(4)))  unsigned short u16x4;

__device__ __forceinline__ unsigned short f2bf(float f) {
    union { float f; unsigned u; } v; v.f = f;
    unsigned r = v.u + 0x7fffu + ((v.u >> 16) & 1u);   // RNE
    return (unsigned short)(r >> 16);
}

__device__ __forceinline__ float bf2f(unsigned u) {
    union { unsigned i; float f; } v; v.i = u << 16; return v.f;
}

// lo16(a) -> low half, lo16(b) -> high half, one v_perm_b32
__device__ __forceinline__ unsigned pk(unsigned a, unsigned b) {
    return __builtin_amdgcn_perm(b, a, 0x05040100u);
}

__device__ __forceinline__ short8 mk8(unsigned u0, unsigned u1, unsigned u2, unsigned u3) {
    union { unsigned u[4]; short8 s; } p;
    p.u[0] = u0; p.u[1] = u1; p.u[2] = u2; p.u[3] = u3;
    return p.s;
}

// ---- pre-pass: x fp32 -> bf16 (RNE) into workspace.
__global__ void xcvt(const float* __restrict__ x, unsigned short* __restrict__ xb, int n4) {
    int i = blockIdx.x * blockDim.x + threadIdx.x;
    if (i < n4) {
        f32x4 v = __builtin_nontemporal_load(((const f32x4*)x) + i);
        u16x4 o;
        o.x = f2bf(v.x); o.y = f2bf(v.y); o.z = f2bf(v.z); o.w = f2bf(v.w);
        __builtin_nontemporal_store(o, ((u16x4*)xb) + i);
    }
}

__global__ __launch_bounds__(TPB, 4) void gnn(
    const unsigned short* __restrict__ xb,   // [N,24] bf16 (gather table + epilogue)
    const int*            __restrict__ ei,   // [2,E]; row 0 = src
    const float*          __restrict__ kv,   // [2,E]
    const float*          __restrict__ W,    // [64,48]
    float*                __restrict__ out)  // [N,64]
{
    __shared__ int            ei_s[NPB * DEG];       // 4 KB: src*48 byte offsets
    __shared__ unsigned short kv_s[2 * NPB * DEG];   // 4 KB bf16 kvals
    __shared__ unsigned short pre_s[NPB * PST];      // 3.5 KB bf16 pre rows

    const int t    = threadIdx.x;
    const int lane = t & 63;
    const int w    = t >> 6;
    const int m    = lane & 31;      // A-row / B-col / C-col
    const int kh   = lane >> 5;      // K-half
    const int kh8  = kh * 8;
    const int base = blockIdx.x * NPB;
    const int dclamp = (m < DD) ? m : (DD - 1);
    const int m2     = dclamp * 2;   // byte offset within row
    const char* xbc  = (const char*)xb;

    // ---- cooperative staging: ei row0 (pre-scaled *48) + both kv rows (bf16)
    // Streamed exactly once across the whole grid -> nontemporal, keep the
    // gather table resident in L2 instead.
    {
        const size_t eb = (size_t)base * DEG;        // 1024 edges per block
        i32x4 ev = __builtin_nontemporal_load(((const i32x4*)(ei + eb)) + t);
        ev.x *= 48; ev.y *= 48; ev.z *= 48; ev.w *= 48;
        ((i32x4*)ei_s)[t] = ev;
        const f32x4 c0 = __builtin_nontemporal_load(((const f32x4*)(kv + eb)) + t);
        const f32x4 c1 = __builtin_nontemporal_load(((const f32x4*)(kv + EE + eb)) + t);
        u16x4 u0, u1;
        u0.x = f2bf(c0.x); u0.y = f2bf(c0.y); u0.z = f2bf(c0.z); u0.w = f2bf(c0.w);
        u1.x = f2bf(c1.x); u1.y = f2bf(c1.y); u1.z = f2bf(c1.z); u1.w = f2bf(c1.w);
        ((u16x4*)kv_s)[t] = u0;
        ((u16x4*)(kv_s + NPB * DEG))[t] = u1;
    }
    __syncthreads();

    // ================= Phase 1: depth-3 pipelined aggregation =================
    const unsigned short* kvrow = kv_s + (m & 1) * (NPB * DEG);  // m=0 -> k0, m=1 -> k1

    unsigned g[3][16];
    unsigned xv[3];

    #define LOAD_NODE(nl, sl) do {                                             \
        const int el_ = (nl) * DEG + kh8;                                      \
        const i32x4 s0_ = *(const i32x4*)(ei_s + el_);                         \
        const i32x4 s1_ = *(const i32x4*)(ei_s + el_ + 4);                     \
        const i32x4 s2_ = *(const i32x4*)(ei_s + el_ + 16);                    \
        const i32x4 s3_ = *(const i32x4*)(ei_s + el_ + 20);                    \
        g[sl][0]  = *(const unsigned short*)(xbc + (unsigned)(s0_.x + m2));    \
        g[sl][1]  = *(const unsigned short*)(xbc + (unsigned)(s0_.y + m2));    \
        g[sl][2]  = *(const unsigned short*)(xbc + (unsigned)(s0_.z + m2));    \
        g[sl][3]  = *(const unsigned short*)(xbc + (unsigned)(s0_.w + m2));    \
        g[sl][4]  = *(const unsigned short*)(xbc + (unsigned)(s1_.x + m2));    \
        g[sl][5]  = *(const unsigned short*)(xbc + (unsigned)(s1_.y + m2));    \
        g[sl][6]  = *(const unsigned short*)(xbc + (unsigned)(s1_.z + m2));    \
        g[sl][7]  = *(const unsigned short*)(xbc + (unsigned)(s1_.w + m2));    \
        g[sl][8]  = *(const unsigned short*)(xbc + (unsigned)(s2_.x + m2));    \
        g[sl][9]  = *(const unsigned short*)(xbc + (unsigned)(s2_.y + m2));    \
        g[sl][10] = *(const unsigned short*)(xbc + (unsigned)(s2_.z + m2));    \
        g[sl][11] = *(const unsigned short*)(xbc + (unsigned)(s2_.w + m2));    \
        g[sl][12] = *(const unsigned short*)(xbc + (unsigned)(s3_.x + m2));    \
        g[sl][13] = *(const unsigned short*)(xbc + (unsigned)(s3_.y + m2));    \
        g[sl][14] = *(const unsigned short*)(xbc + (unsigned)(s3_.z + m2));    \
        g[sl][15] = *(const unsigned short*)(xbc + (unsigned)(s3_.w + m2));    \
        xv[sl] = xb[(base + (nl)) * DD + dclamp];                              \
    } while (0)

    LOAD_NODE(w * NPW + 0, 0);
    LOAD_NODE(w * NPW + 1, 1);

    #pragma unroll
    for (int i = 0; i < NPW; ++i) {
        const int cur = i % 3;                       // compile-time after unroll
        const int nl  = w * NPW + i;
        if (i < NPW - 2) LOAD_NODE(nl + 2, (i + 2) % 3);   // prefetch node i+2

        // A fragments from LDS (broadcast within half-wave, conflict-free)
        const int el = nl * DEG + kh8;
        const short8 raw0 = *(const short8*)(kvrow + el);
        const short8 raw1 = *(const short8*)(kvrow + el + 16);
        const unsigned fill = (m == 2) ? 0x3F803F80u : 0u;   // bf16 ones row / zeros
        const short8 af0 = (m < 2) ? raw0 : mk8(fill, fill, fill, fill);
        const short8 af1 = (m < 2) ? raw1 : mk8(fill, fill, fill, fill);

        const short8 bf0 = mk8(pk(g[cur][0],  g[cur][1]),  pk(g[cur][2],  g[cur][3]),
                               pk(g[cur][4],  g[cur][5]),  pk(g[cur][6],  g[cur][7]));
        const short8 bf1 = mk8(pk(g[cur][8],  g[cur][9]),  pk(g[cur][10], g[cur][11]),
                               pk(g[cur][12], g[cur][13]), pk(g[cur][14], g[cur][15]));

        float16 acc;
        #pragma unroll
        for (int r = 0; r < 16; ++r) acc[r] = 0.f;
        acc = __builtin_amdgcn_mfma_f32_32x32x16_bf16(af0, bf0, acc, 0, 0, 0);
        acc = __builtin_amdgcn_mfma_f32_32x32x16_bf16(af1, bf1, acc, 0, 0, 0);

        // rows 0(a0),1(a1),2(sum) live in regs 0,1,2 of kh==0 lanes
        if (kh == 0 && m < DD) {
            const float sm = acc[2] * (1.f / 32.f);
            const float pv = bf2f(xv[cur]) - sm;
            pre_s[nl * PST + m]      = f2bf(acc[0] + pv);
            pre_s[nl * PST + 24 + m] = f2bf(acc[1] + pv);
        }
    }
    #undef LOAD_NODE
    __syncthreads();

    // ================= Phase 2: out(32x64) = pre(32x48) @ W^T, waves 0,1 =================
    if (w < 2) {
        const int h = w * 32 + m;

        float16 acc;
        #pragma unroll
        for (int r = 0; r < 16; ++r) acc[r] = 0.f;

        #pragma unroll
        for (int kc = 0; kc < 3; ++kc) {
            const int c0 = kc * 16 + kh8;
            const short8 af = *(const short8*)(pre_s + m * PST + c0);
            const float* wr = W + h * 48 + c0;
            const f32x4 wA = ((const f32x4*)wr)[0];
            const f32x4 wB = ((const f32x4*)wr)[1];
            const short8 bf = mk8(pk(f2bf(wA.x), f2bf(wA.y)), pk(f2bf(wA.z), f2bf(wA.w)),
                                  pk(f2bf(wB.x), f2bf(wB.y)), pk(f2bf(wB.z), f2bf(wB.w)));
            acc = __builtin_amdgcn_mfma_f32_32x32x16_bf16(af, bf, acc, 0, 0, 0);
        }

        #pragma unroll
        for (int r = 0; r < 16; ++r) {
            const int row = (r & 3) + 8 * (r >> 2) + 4 * kh;   // node within block
            __builtin_nontemporal_store(acc[r], &out[(size_t)(base + row) * HH + h]);
        }
    }
}

extern "C" void kernel_launch(void* const* d_in, const int* in_sizes, int n_in,
                              void* d_out, int out_size, void* d_ws, size_t ws_size,
                              hipStream_t stream) {
    const float* x  = (const float*)d_in[0];
    const int*   ei = (const int*)d_in[1];
    const float* kv = (const float*)d_in[2];
    const float* W  = (const float*)d_in[3];
    float* out = (float*)d_out;

    unsigned short* xb = (unsigned short*)d_ws;            // 4.8 MB scratch
    const int n4 = NN * DD / 4;                            // 600000
    xcvt<<<(n4 + 255) / 256, 256, 0, stream>>>(x, xb, n4);

    const int grid = NN / NPB;                             // 3125, exact
    gnn<<<grid, TPB, 0, stream>>>(xb, ei, kv, W, out);
}

// Round 3
// 129.097 us; speedup vs baseline: 1.0168x; 1.0168x over previous
//
#include <hip/hip_runtime.h>

// net_86698209837440: N=100000, DEG=32 (edges sorted by tgt, deg==32), D=24, NK=2, H=64.
// R10: gang-gather restructure. Phase-1 gathers were 16x 2-byte scattered loads
// per node per wave (in-order vmcnt => every node pays max-of-48-lines latency,
// TA processes ~6600 divergent insts/CU). Now:
//  - xb padded to 64B rows ([N][32] bf16): one aligned line per row.
//  - per 2-node gang: 4 dwordx4 loads/lane, quad-coalesced (lanes 4k..4k+3 cover
//    one full row) -> 2 gather VMEM insts/node, 16 line-transactions/inst.
//  - rows land in a wave-private 4KB LDS tile (row-bit3 XOR swizzle, fragment
//    reads 2-way max = free); B-fragments via 16 ds_read_u16 + 8 v_perm/node.
//  - depth-2 gang pipeline (G[2][4] regs): one vmcnt event per gang.
// Math identical to R7/R9 (same edge->K mapping, fragments, epilogue).

#define NN   100000
#define DEG  32
#define EE   (NN * DEG)
#define DD   24
#define HH   64
#define NPB  32            // nodes per block; 100000 = 3125 * 32 exact
#define TPB  256
#define NPW  8             // nodes per wave (4 gangs of 2)
#define PST  56            // pre_s row stride (ushorts)
#define XRU  32            // padded xb row length in u16 (64 bytes)

typedef __attribute__((ext_vector_type(8)))  short short8;
typedef __attribute__((ext_vector_type(16))) float float16;
typedef __attribute__((ext_vector_type(4)))  float f32x4;
typedef __attribute__((ext_vector_type(4)))  int   i32x4;
typedef __attribute__((ext_vector_type(4)))  unsigned short u16x4;

__device__ __forceinline__ unsigned short f2bf(float f) {
    union { float f; unsigned u; } v; v.f = f;
    unsigned r = v.u + 0x7fffu + ((v.u >> 16) & 1u);   // RNE
    return (unsigned short)(r >> 16);
}

__device__ __forceinline__ float bf2f(unsigned u) {
    union { unsigned i; float f; } v; v.i = u << 16; return v.f;
}

// lo16(a) -> low half, lo16(b) -> high half, one v_perm_b32
__device__ __forceinline__ unsigned pk(unsigned a, unsigned b) {
    return __builtin_amdgcn_perm(b, a, 0x05040100u);
}

__device__ __forceinline__ short8 mk8(unsigned u0, unsigned u1, unsigned u2, unsigned u3) {
    union { unsigned u[4]; short8 s; } p;
    p.u[0] = u0; p.u[1] = u1; p.u[2] = u2; p.u[3] = u3;
    return p.s;
}

// ---- pre-pass: x fp32 [N][24] -> bf16 padded [N][32] (64B rows).
// chunk c (f32x4) -> row c/6, pos c%6 -> u16x4 at row*32 + pos*4.
// Pad bytes 48..63 are never read by compute (fragment reads use m2 <= 46).
__global__ void xcvt(const float* __restrict__ x, unsigned short* __restrict__ xb, int n6) {
    int c = blockIdx.x * blockDim.x + threadIdx.x;
    if (c < n6) {
        int row = c / 6;
        int pos = c - row * 6;
        f32x4 v = __builtin_nontemporal_load(((const f32x4*)x) + c);
        u16x4 o;
        o.x = f2bf(v.x); o.y = f2bf(v.y); o.z = f2bf(v.z); o.w = f2bf(v.w);
        ((u16x4*)xb)[row * 8 + pos] = o;
    }
}

__global__ __launch_bounds__(TPB, 4) void gnn(
    const unsigned short* __restrict__ xb,   // [N,32] bf16 padded (gather table)
    const int*            __restrict__ ei,   // [2,E]; row 0 = src
    const float*          __restrict__ kv,   // [2,E]
    const float*          __restrict__ W,    // [64,48]
    float*                __restrict__ out)  // [N,64]
{
    __shared__ int            ei_s[NPB * DEG];       // 4 KB: src*64 byte offsets
    __shared__ unsigned short kv_s[2 * NPB * DEG];   // 4 KB bf16 kvals
    __shared__ unsigned short pre_s[NPB * PST];      // 3.5 KB bf16 pre rows
    __shared__ unsigned short xs_s[4][64 * XRU];     // 16 KB: per-wave gang tile

    const int t    = threadIdx.x;
    const int lane = t & 63;
    const int w    = t >> 6;
    const int m    = lane & 31;      // A-row / B-col / C-col
    const int kh   = lane >> 5;      // K-half
    const int kh8  = kh * 8;
    const int base = blockIdx.x * NPB;
    const int dclamp = (m < DD) ? m : (DD - 1);
    const int m2     = dclamp * 2;   // byte offset within row
    const char* xbc  = (const char*)xb;

    // gang-gather geometry (per lane)
    const int er   = lane >> 2;                        // edge-slot within 16
    const int q16  = (lane & 3) * 16;                  // 16B chunk within row
    char* xsb = (char*)&xs_s[w][0];                    // wave-private 4KB tile
    const unsigned wswz = (unsigned)((lane & 32) << 1);  // write xor: ((row&8)<<3)
    const unsigned fswz = (unsigned)(kh << 6);           // frag-read xor

    // ---- cooperative staging: ei row0 (pre-scaled *64) + both kv rows (bf16)
    {
        const size_t eb = (size_t)base * DEG;        // 1024 edges per block
        i32x4 ev = __builtin_nontemporal_load(((const i32x4*)(ei + eb)) + t);
        ev.x <<= 6; ev.y <<= 6; ev.z <<= 6; ev.w <<= 6;
        ((i32x4*)ei_s)[t] = ev;
        const f32x4 c0 = __builtin_nontemporal_load(((const f32x4*)(kv + eb)) + t);
        const f32x4 c1 = __builtin_nontemporal_load(((const f32x4*)(kv + EE + eb)) + t);
        u16x4 u0, u1;
        u0.x = f2bf(c0.x); u0.y = f2bf(c0.y); u0.z = f2bf(c0.z); u0.w = f2bf(c0.w);
        u1.x = f2bf(c1.x); u1.y = f2bf(c1.y); u1.z = f2bf(c1.z); u1.w = f2bf(c1.w);
        ((u16x4*)kv_s)[t] = u0;
        ((u16x4*)(kv_s + NPB * DEG))[t] = u1;
    }
    __syncthreads();

    // ================= Phase 1: gang-pipelined aggregation =================
    const unsigned short* kvrow = kv_s + (m & 1) * (NPB * DEG);  // m=0 -> k0, m=1 -> k1

    i32x4 G[2][4];
    unsigned short xvv[2][2];

    // load 64 rows (2 nodes) of gathered x into regs; lanes 4k..4k+3 cover row k
    #define GATHER_GANG(gg, sl) do {                                           \
        const int eb_ = (w * NPW + 2 * (gg)) * DEG;                            \
        const int o0_ = ei_s[eb_ +  0 + er];                                   \
        const int o1_ = ei_s[eb_ + 16 + er];                                   \
        const int o2_ = ei_s[eb_ + 32 + er];                                   \
        const int o3_ = ei_s[eb_ + 48 + er];                                   \
        G[sl][0] = *(const i32x4*)(xbc + (unsigned)(o0_ + q16));               \
        G[sl][1] = *(const i32x4*)(xbc + (unsigned)(o1_ + q16));               \
        G[sl][2] = *(const i32x4*)(xbc + (unsigned)(o2_ + q16));               \
        G[sl][3] = *(const i32x4*)(xbc + (unsigned)(o3_ + q16));               \
        xvv[sl][0] = xb[(base + w * NPW + 2 * (gg)) * XRU + dclamp];           \
        xvv[sl][1] = xb[(base + w * NPW + 2 * (gg) + 1) * XRU + dclamp];       \
    } while (0)

    // write gang tile to LDS: row r = j*16+er at (r*64 + q16) ^ ((r&8)<<3)
    #define WRITE_GANG(sl) do {                                                \
        *(i32x4*)(xsb + (((0 * 1024) + er * 64 + q16) ^ wswz)) = G[sl][0];     \
        *(i32x4*)(xsb + (((1 * 1024) + er * 64 + q16) ^ wswz)) = G[sl][1];     \
        *(i32x4*)(xsb + (((2 * 1024) + er * 64 + q16) ^ wswz)) = G[sl][2];     \
        *(i32x4*)(xsb + (((3 * 1024) + er * 64 + q16) ^ wswz)) = G[sl][3];     \
    } while (0)

    #define COMPUTE_NODE(nn, gg, sl) do {                                      \
        const int nl_ = w * NPW + 2 * (gg) + (nn);                             \
        const char* fb_ = xsb + (nn) * 2048 + (kh << 9);                       \
        unsigned ga_[8], gb_[8];                                               \
        _Pragma("unroll")                                                      \
        for (int j = 0; j < 8; ++j)                                            \
            ga_[j] = *(const unsigned short*)(fb_ + (((j << 6) + m2) ^ fswz)); \
        _Pragma("unroll")                                                      \
        for (int j = 0; j < 8; ++j)                                            \
            gb_[j] = *(const unsigned short*)(fb_ + 1024 + (((j << 6) + m2) ^ fswz)); \
        const int el_ = nl_ * DEG + kh8;                                       \
        const short8 raw0_ = *(const short8*)(kvrow + el_);                    \
        const short8 raw1_ = *(const short8*)(kvrow + el_ + 16);               \
        const unsigned fill_ = (m == 2) ? 0x3F803F80u : 0u;                    \
        const short8 af0_ = (m < 2) ? raw0_ : mk8(fill_, fill_, fill_, fill_); \
        const short8 af1_ = (m < 2) ? raw1_ : mk8(fill_, fill_, fill_, fill_); \
        const short8 bf0_ = mk8(pk(ga_[0], ga_[1]), pk(ga_[2], ga_[3]),        \
                                pk(ga_[4], ga_[5]), pk(ga_[6], ga_[7]));       \
        const short8 bf1_ = mk8(pk(gb_[0], gb_[1]), pk(gb_[2], gb_[3]),        \
                                pk(gb_[4], gb_[5]), pk(gb_[6], gb_[7]));       \
        float16 acc_;                                                          \
        _Pragma("unroll")                                                      \
        for (int r = 0; r < 16; ++r) acc_[r] = 0.f;                            \
        acc_ = __builtin_amdgcn_mfma_f32_32x32x16_bf16(af0_, bf0_, acc_, 0, 0, 0); \
        acc_ = __builtin_amdgcn_mfma_f32_32x32x16_bf16(af1_, bf1_, acc_, 0, 0, 0); \
        if (kh == 0 && m < DD) {                                               \
            const float sm_ = acc_[2] * (1.f / 32.f);                          \
            const float pv_ = bf2f(xvv[sl][nn]) - sm_;                         \
            pre_s[nl_ * PST + m]      = f2bf(acc_[0] + pv_);                   \
            pre_s[nl_ * PST + 24 + m] = f2bf(acc_[1] + pv_);                   \
        }                                                                      \
    } while (0)

    GATHER_GANG(0, 0);

    #pragma unroll
    for (int gg = 0; gg < NPW / 2; ++gg) {
        const int sl = gg & 1;
        WRITE_GANG(sl);                                  // waits vmcnt on G[sl]
        if (gg < NPW / 2 - 1) GATHER_GANG(gg + 1, sl ^ 1);  // prefetch next gang
        COMPUTE_NODE(0, gg, sl);
        COMPUTE_NODE(1, gg, sl);
    }
    #undef GATHER_GANG
    #undef WRITE_GANG
    #undef COMPUTE_NODE
    __syncthreads();

    // ================= Phase 2: out(32x64) = pre(32x48) @ W^T, waves 0,1 =================
    if (w < 2) {
        const int h = w * 32 + m;

        float16 acc;
        #pragma unroll
        for (int r = 0; r < 16; ++r) acc[r] = 0.f;

        #pragma unroll
        for (int kc = 0; kc < 3; ++kc) {
            const int c0 = kc * 16 + kh8;
            const short8 af = *(const short8*)(pre_s + m * PST + c0);
            const float* wr = W + h * 48 + c0;
            const f32x4 wA = ((const f32x4*)wr)[0];
            const f32x4 wB = ((const f32x4*)wr)[1];
            const short8 bf = mk8(pk(f2bf(wA.x), f2bf(wA.y)), pk(f2bf(wA.z), f2bf(wA.w)),
                                  pk(f2bf(wB.x), f2bf(wB.y)), pk(f2bf(wB.z), f2bf(wB.w)));
            acc = __builtin_amdgcn_mfma_f32_32x32x16_bf16(af, bf, acc, 0, 0, 0);
        }

        #pragma unroll
        for (int r = 0; r < 16; ++r) {
            const int row = (r & 3) + 8 * (r >> 2) + 4 * kh;   // node within block
            __builtin_nontemporal_store(acc[r], &out[(size_t)(base + row) * HH + h]);
        }
    }
}

extern "C" void kernel_launch(void* const* d_in, const int* in_sizes, int n_in,
                              void* d_out, int out_size, void* d_ws, size_t ws_size,
                              hipStream_t stream) {
    const float* x  = (const float*)d_in[0];
    const int*   ei = (const int*)d_in[1];
    const float* kv = (const float*)d_in[2];
    const float* W  = (const float*)d_in[3];
    float* out = (float*)d_out;

    unsigned short* xb = (unsigned short*)d_ws;            // 6.4 MB scratch (padded)
    const int n6 = NN * 6;                                 // 600000 f32x4 chunks
    xcvt<<<(n6 + 255) / 256, 256, 0, stream>>>(x, xb, n6);

    const int grid = NN / NPB;                             // 3125, exact
    gnn<<<grid, TPB, 0, stream>>>(xb, ei, kv, W, out);
}